// Round 1
// baseline (74174.463 us; speedup 1.0000x reference)
//
#include <hip/hip_runtime.h>
#include <math.h>

#define TT 8192
#define DD 128
#define HH 1024
#define RINGN 256          // ring slots (power of 2); actual pipeline lag is ~1-2 steps
#define NA 64              // layer-0 workgroups
#define NB 128             // layer-1 workgroups
#define NC 16              // decoder workgroups
#define NWG (NA + NB + NC)

// d_ws layout (bytes):
//   [0)        a_done  u32[TT]
//   [TT*4)     b_done  u32[TT]
//   [2*TT*4)   c_done  u32[TT]
//   [131072)   h0_ring f32[RINGN][HH]
//   [131072 + RINGN*HH*4) h1_ring f32[RINGN][HH]
// total ~2.2 MB

__device__ __forceinline__ unsigned ldflag(unsigned* p) {
  return __hip_atomic_load(p, __ATOMIC_RELAXED, __HIP_MEMORY_SCOPE_AGENT);
}
__device__ __forceinline__ float ldring(float* p) {
  return __hip_atomic_load(p, __ATOMIC_RELAXED, __HIP_MEMORY_SCOPE_AGENT);
}
__device__ __forceinline__ void st_ring(float* p, float v) {
  __hip_atomic_store(p, v, __ATOMIC_RELAXED, __HIP_MEMORY_SCOPE_AGENT);
}
__device__ __forceinline__ void post(unsigned* p) {
  __hip_atomic_fetch_add(p, 1u, __ATOMIC_RELEASE, __HIP_MEMORY_SCOPE_AGENT);
}
__device__ __forceinline__ void waitge(unsigned* p, unsigned v) {
  while (ldflag(p) < v) __builtin_amdgcn_s_sleep(1);
}
__device__ __forceinline__ float sigm(float x) { return 1.0f / (1.0f + expf(-x)); }
__device__ __forceinline__ float softplusf(float x) {
  return x > 0.0f ? x + log1pf(expf(-x)) : log1pf(expf(x));
}

__global__ void __launch_bounds__(256, 1) deepar_persistent(
    const float* __restrict__ obs,
    const float* __restrict__ Wih0, const float* __restrict__ Whh0, const float* __restrict__ b0,
    const float* __restrict__ Wih1, const float* __restrict__ Whh1, const float* __restrict__ b1,
    const float* __restrict__ Wdec, const float* __restrict__ bdec,
    float* __restrict__ out,
    unsigned* a_done, unsigned* b_done, unsigned* c_done,
    float* h0_ring, float* h1_ring)
{
  // hx padded by +4 words per chunk to break LDS bank conflicts on float4 reads
  __shared__ __align__(16) float hx[2176];
  __shared__ float zbuf[64];
  __shared__ float zbias[64];
  __shared__ float cst[16];

  const int wg  = blockIdx.x;
  const int tid = threadIdx.x;

  if (wg < NA) {
    //================= Group A: layer-0 LSTM (owns 16 h-indices) =================
    const int rg = tid >> 4;   // 0..15, 4 gate-rows each
    const int q  = tid & 15;   // 0..15, 72-wide k-chunk of [h0(1024); x(128)]
    const int jb = wg * 16;
    float w[4][72];            // VGPR-resident weights
    {
      const int k0 = q * 72;
      #pragma unroll
      for (int i = 0; i < 18; ++i) {
        const int kb = k0 + 4 * i;
        #pragma unroll
        for (int r = 0; r < 4; ++r) {
          const int rr   = 4 * rg + r;                      // local row 0..63
          const int grow = (rr >> 4) * HH + jb + (rr & 15); // gate*1024 + j
          const float* src = (kb < HH) ? (Whh0 + (size_t)grow * HH + kb)
                                       : (Wih0 + (size_t)grow * DD + (kb - HH));
          const float4 v = *(const float4*)src;
          w[r][4*i+0] = v.x; w[r][4*i+1] = v.y; w[r][4*i+2] = v.z; w[r][4*i+3] = v.w;
        }
      }
    }
    if (tid < 64) zbias[tid] = b0[(tid >> 4) * HH + jb + (tid & 15)];
    if (tid < 16) cst[tid] = 0.0f;
    __syncthreads();

    for (int t = 0; t < TT; ++t) {
      if (tid == 0) {
        if (t > 0)      waitge(&a_done[t - 1], NA);       // need full h0(t-1)
        if (t >= RINGN) waitge(&b_done[t - RINGN], NB);   // ring backpressure
      }
      __syncthreads();
      {
        const int slot = (t - 1) & (RINGN - 1);
        for (int idx = tid; idx < HH + DD; idx += 256) {
          float v;
          if (idx < HH) v = (t > 0) ? ldring(&h0_ring[(size_t)slot * HH + idx]) : 0.0f;
          else          v = (t > 0) ? obs[(size_t)(t - 1) * DD + (idx - HH)] : 0.0f;
          hx[idx + 4 * (idx / 72)] = v;
        }
      }
      __syncthreads();
      float a0 = 0.f, a1 = 0.f, a2 = 0.f, a3 = 0.f;
      {
        const int base = q * 76;
        #pragma unroll
        for (int i = 0; i < 18; ++i) {
          const float4 h4 = *(const float4*)&hx[base + 4 * i];
          a0 = fmaf(w[0][4*i+0], h4.x, a0); a0 = fmaf(w[0][4*i+1], h4.y, a0);
          a0 = fmaf(w[0][4*i+2], h4.z, a0); a0 = fmaf(w[0][4*i+3], h4.w, a0);
          a1 = fmaf(w[1][4*i+0], h4.x, a1); a1 = fmaf(w[1][4*i+1], h4.y, a1);
          a1 = fmaf(w[1][4*i+2], h4.z, a1); a1 = fmaf(w[1][4*i+3], h4.w, a1);
          a2 = fmaf(w[2][4*i+0], h4.x, a2); a2 = fmaf(w[2][4*i+1], h4.y, a2);
          a2 = fmaf(w[2][4*i+2], h4.z, a2); a2 = fmaf(w[2][4*i+3], h4.w, a2);
          a3 = fmaf(w[3][4*i+0], h4.x, a3); a3 = fmaf(w[3][4*i+1], h4.y, a3);
          a3 = fmaf(w[3][4*i+2], h4.z, a3); a3 = fmaf(w[3][4*i+3], h4.w, a3);
        }
      }
      #pragma unroll
      for (int m = 1; m < 16; m <<= 1) {
        a0 += __shfl_xor(a0, m); a1 += __shfl_xor(a1, m);
        a2 += __shfl_xor(a2, m); a3 += __shfl_xor(a3, m);
      }
      if (q == 0) {
        zbuf[4*rg+0] = a0 + zbias[4*rg+0];
        zbuf[4*rg+1] = a1 + zbias[4*rg+1];
        zbuf[4*rg+2] = a2 + zbias[4*rg+2];
        zbuf[4*rg+3] = a3 + zbias[4*rg+3];
      }
      __syncthreads();
      if (tid < 16) {
        const float ig = sigm(zbuf[tid]);
        const float fg = sigm(zbuf[16 + tid]);
        const float gg = tanhf(zbuf[32 + tid]);
        const float og = sigm(zbuf[48 + tid]);
        const float c  = fg * cst[tid] + ig * gg;
        cst[tid] = c;
        st_ring(&h0_ring[(size_t)(t & (RINGN - 1)) * HH + jb + tid], og * tanhf(c));
      }
      __syncthreads();   // all consumption of hx + ring stores done
      if (tid == 0) post(&a_done[t]);
    }

  } else if (wg < NA + NB) {
    //================= Group B: layer-1 LSTM (owns 8 h-indices) =================
    const int rg = tid >> 5;   // 0..7, 4 gate-rows each
    const int q  = tid & 31;   // 0..31, 64-wide k-chunk of [h0(t); h1(t-1)]
    const int jb = (wg - NA) * 8;
    float w[4][64];
    {
      const int k0 = q * 64;
      #pragma unroll
      for (int i = 0; i < 16; ++i) {
        const int kb = k0 + 4 * i;
        #pragma unroll
        for (int r = 0; r < 4; ++r) {
          const int rr   = 4 * rg + r;                     // local row 0..31
          const int grow = (rr >> 3) * HH + jb + (rr & 7);
          const float* src = (kb < HH) ? (Wih1 + (size_t)grow * HH + kb)
                                       : (Whh1 + (size_t)grow * HH + (kb - HH));
          const float4 v = *(const float4*)src;
          w[r][4*i+0] = v.x; w[r][4*i+1] = v.y; w[r][4*i+2] = v.z; w[r][4*i+3] = v.w;
        }
      }
    }
    if (tid < 32) zbias[tid] = b1[(tid >> 3) * HH + jb + (tid & 7)];
    if (tid < 8)  cst[tid] = 0.0f;
    __syncthreads();

    for (int t = 0; t < TT; ++t) {
      if (tid == 0) {
        waitge(&a_done[t], NA);                           // need h0(t)
        if (t > 0)      waitge(&b_done[t - 1], NB);       // need full h1(t-1)
        if (t >= RINGN) waitge(&c_done[t - RINGN], NC);   // ring backpressure
      }
      __syncthreads();
      {
        const int s0 = t & (RINGN - 1);
        const int s1 = (t - 1) & (RINGN - 1);
        for (int idx = tid; idx < 2 * HH; idx += 256) {
          float v;
          if (idx < HH) v = ldring(&h0_ring[(size_t)s0 * HH + idx]);
          else          v = (t > 0) ? ldring(&h1_ring[(size_t)s1 * HH + (idx - HH)]) : 0.0f;
          hx[idx + ((idx >> 6) << 2)] = v;
        }
      }
      __syncthreads();
      float a0 = 0.f, a1 = 0.f, a2 = 0.f, a3 = 0.f;
      {
        const int base = q * 68;
        #pragma unroll
        for (int i = 0; i < 16; ++i) {
          const float4 h4 = *(const float4*)&hx[base + 4 * i];
          a0 = fmaf(w[0][4*i+0], h4.x, a0); a0 = fmaf(w[0][4*i+1], h4.y, a0);
          a0 = fmaf(w[0][4*i+2], h4.z, a0); a0 = fmaf(w[0][4*i+3], h4.w, a0);
          a1 = fmaf(w[1][4*i+0], h4.x, a1); a1 = fmaf(w[1][4*i+1], h4.y, a1);
          a1 = fmaf(w[1][4*i+2], h4.z, a1); a1 = fmaf(w[1][4*i+3], h4.w, a1);
          a2 = fmaf(w[2][4*i+0], h4.x, a2); a2 = fmaf(w[2][4*i+1], h4.y, a2);
          a2 = fmaf(w[2][4*i+2], h4.z, a2); a2 = fmaf(w[2][4*i+3], h4.w, a2);
          a3 = fmaf(w[3][4*i+0], h4.x, a3); a3 = fmaf(w[3][4*i+1], h4.y, a3);
          a3 = fmaf(w[3][4*i+2], h4.z, a3); a3 = fmaf(w[3][4*i+3], h4.w, a3);
        }
      }
      #pragma unroll
      for (int m = 1; m < 32; m <<= 1) {
        a0 += __shfl_xor(a0, m); a1 += __shfl_xor(a1, m);
        a2 += __shfl_xor(a2, m); a3 += __shfl_xor(a3, m);
      }
      if (q == 0) {
        zbuf[4*rg+0] = a0 + zbias[4*rg+0];
        zbuf[4*rg+1] = a1 + zbias[4*rg+1];
        zbuf[4*rg+2] = a2 + zbias[4*rg+2];
        zbuf[4*rg+3] = a3 + zbias[4*rg+3];
      }
      __syncthreads();
      if (tid < 8) {
        const float ig = sigm(zbuf[tid]);
        const float fg = sigm(zbuf[8 + tid]);
        const float gg = tanhf(zbuf[16 + tid]);
        const float og = sigm(zbuf[24 + tid]);
        const float c  = fg * cst[tid] + ig * gg;
        cst[tid] = c;
        st_ring(&h1_ring[(size_t)(t & (RINGN - 1)) * HH + jb + tid], og * tanhf(c));
      }
      __syncthreads();
      if (tid == 0) post(&b_done[t]);
    }

  } else {
    //================= Group C: decoder (16 rows of W_dec each) =================
    const int rg = tid >> 6;   // 0..3, 4 rows each
    const int q  = tid & 63;   // 16-wide k-chunk of h1
    const int rowbase = (wg - NA - NB) * 16;
    float w[4][16];
    {
      const int k0 = q * 16;
      #pragma unroll
      for (int i = 0; i < 4; ++i) {
        const int kb = k0 + 4 * i;
        #pragma unroll
        for (int r = 0; r < 4; ++r) {
          const int grow = rowbase + 4 * rg + r;
          const float4 v = *(const float4*)(Wdec + (size_t)grow * HH + kb);
          w[r][4*i+0] = v.x; w[r][4*i+1] = v.y; w[r][4*i+2] = v.z; w[r][4*i+3] = v.w;
        }
      }
    }
    if (tid < 16) zbias[tid] = bdec[rowbase + tid];
    __syncthreads();

    for (int t = 0; t < TT; ++t) {
      if (tid == 0) waitge(&b_done[t], NB);   // need h1(t)
      __syncthreads();
      {
        const int s0 = t & (RINGN - 1);
        for (int idx = tid; idx < HH; idx += 256)
          hx[idx + ((idx >> 4) << 2)] = ldring(&h1_ring[(size_t)s0 * HH + idx]);
      }
      __syncthreads();
      float a0 = 0.f, a1 = 0.f, a2 = 0.f, a3 = 0.f;
      {
        const int base = q * 20;
        #pragma unroll
        for (int i = 0; i < 4; ++i) {
          const float4 h4 = *(const float4*)&hx[base + 4 * i];
          a0 = fmaf(w[0][4*i+0], h4.x, a0); a0 = fmaf(w[0][4*i+1], h4.y, a0);
          a0 = fmaf(w[0][4*i+2], h4.z, a0); a0 = fmaf(w[0][4*i+3], h4.w, a0);
          a1 = fmaf(w[1][4*i+0], h4.x, a1); a1 = fmaf(w[1][4*i+1], h4.y, a1);
          a1 = fmaf(w[1][4*i+2], h4.z, a1); a1 = fmaf(w[1][4*i+3], h4.w, a1);
          a2 = fmaf(w[2][4*i+0], h4.x, a2); a2 = fmaf(w[2][4*i+1], h4.y, a2);
          a2 = fmaf(w[2][4*i+2], h4.z, a2); a2 = fmaf(w[2][4*i+3], h4.w, a2);
          a3 = fmaf(w[3][4*i+0], h4.x, a3); a3 = fmaf(w[3][4*i+1], h4.y, a3);
          a3 = fmaf(w[3][4*i+2], h4.z, a3); a3 = fmaf(w[3][4*i+3], h4.w, a3);
        }
      }
      #pragma unroll
      for (int m = 1; m < 64; m <<= 1) {
        a0 += __shfl_xor(a0, m); a1 += __shfl_xor(a1, m);
        a2 += __shfl_xor(a2, m); a3 += __shfl_xor(a3, m);
      }
      if (q == 0) {
        const float zz[4] = { a0, a1, a2, a3 };
        #pragma unroll
        for (int r = 0; r < 4; ++r) {
          const int lr   = 4 * rg + r;
          const int grow = rowbase + lr;
          const float z  = zz[r] + zbias[lr];
          if (grow < DD) out[(size_t)t * DD + grow] = z;                      // loc
          else out[(size_t)TT * DD + (size_t)t * DD + (grow - DD)]
                 = softplusf(z) + 1e-4f;                                      // scale
        }
      }
      __syncthreads();   // all h1-ring reads of this step complete
      if (tid == 0) post(&c_done[t]);
    }
  }
}

extern "C" void kernel_launch(void* const* d_in, const int* in_sizes, int n_in,
                              void* d_out, int out_size, void* d_ws, size_t ws_size,
                              hipStream_t stream) {
  const float* obs  = (const float*)d_in[0];
  const float* Wih0 = (const float*)d_in[1];
  const float* Whh0 = (const float*)d_in[2];
  const float* b0   = (const float*)d_in[3];
  const float* Wih1 = (const float*)d_in[4];
  const float* Whh1 = (const float*)d_in[5];
  const float* b1   = (const float*)d_in[6];
  const float* Wdec = (const float*)d_in[7];
  const float* bdec = (const float*)d_in[8];
  float* out = (float*)d_out;

  unsigned char* ws = (unsigned char*)d_ws;
  unsigned* a_done = (unsigned*)(ws);
  unsigned* b_done = (unsigned*)(ws + (size_t)TT * 4);
  unsigned* c_done = (unsigned*)(ws + (size_t)2 * TT * 4);
  float* h0_ring = (float*)(ws + 131072);
  float* h1_ring = (float*)(ws + 131072 + (size_t)RINGN * HH * 4);

  // flags must be zero each call (graph replays; harness does not re-poison)
  hipMemsetAsync(ws, 0, (size_t)3 * TT * 4, stream);

  hipLaunchKernelGGL(deepar_persistent, dim3(NWG), dim3(256), 0, stream,
                     obs, Wih0, Whh0, b0, Wih1, Whh1, b1, Wdec, bdec, out,
                     a_done, b_done, c_done, h0_ring, h1_ring);
}